// Round 1
// baseline (1767.419 us; speedup 1.0000x reference)
//
#include <hip/hip_runtime.h>
#include <cstdint>
#include <cstddef>

// ---------------------------------------------------------------------------
// Generic NT GEMM: C[M,N] = A[M,K] @ W[N,K]^T  (both row-major, K contiguous)
// mode 0: plain store.  mode 1: C = softplus(acc + bias[n])
// 64x64 tile, BK=16, 256 threads, 4x4 micro-tile per thread.
// LDS stored transposed (As[k][m]) so fragment loads are ds_read_b128.
// ---------------------------------------------------------------------------
#define BM 64
#define BN 64
#define BK 16
#define BMP 68   // padded leading dim (floats) to spread banks
#define BNP 68

__global__ __launch_bounds__(256)
void gemm_nt(const float* __restrict__ A, int lda,
             const float* __restrict__ W, int ldw,
             float* __restrict__ C, int ldc,
             int M, int N, int K,
             const float* __restrict__ bias, int mode)
{
    __shared__ float As[BK][BMP];
    __shared__ float Ws[BK][BNP];

    const int tid  = threadIdx.x;
    const int row0 = blockIdx.y * BM;
    const int col0 = blockIdx.x * BN;
    const int lr = tid >> 2;          // 0..63  loader row within tile
    const int lk = (tid & 3) << 2;    // 0,4,8,12 loader k offset
    const int tx = tid & 15;          // 0..15  micro-tile col group
    const int ty = tid >> 4;          // 0..15  micro-tile row group

    float acc[4][4];
#pragma unroll
    for (int i = 0; i < 4; ++i)
#pragma unroll
        for (int j = 0; j < 4; ++j) acc[i][j] = 0.f;

    for (int k0 = 0; k0 < K; k0 += BK) {
        float4 av = make_float4(0.f, 0.f, 0.f, 0.f);
        float4 wv = make_float4(0.f, 0.f, 0.f, 0.f);
        const int ar = row0 + lr;
        if (ar < M) av = *(const float4*)(A + (size_t)ar * lda + k0 + lk);
        const int wr = col0 + lr;
        if (wr < N) wv = *(const float4*)(W + (size_t)wr * ldw + k0 + lk);

        As[lk + 0][lr] = av.x; As[lk + 1][lr] = av.y;
        As[lk + 2][lr] = av.z; As[lk + 3][lr] = av.w;
        Ws[lk + 0][lr] = wv.x; Ws[lk + 1][lr] = wv.y;
        Ws[lk + 2][lr] = wv.z; Ws[lk + 3][lr] = wv.w;
        __syncthreads();

#pragma unroll
        for (int kk = 0; kk < BK; ++kk) {
            float4 a = *(const float4*)&As[kk][ty * 4];
            float4 w = *(const float4*)&Ws[kk][tx * 4];
            float ai[4] = {a.x, a.y, a.z, a.w};
            float wj[4] = {w.x, w.y, w.z, w.w};
#pragma unroll
            for (int i = 0; i < 4; ++i)
#pragma unroll
                for (int j = 0; j < 4; ++j)
                    acc[i][j] = fmaf(ai[i], wj[j], acc[i][j]);
        }
        __syncthreads();
    }

#pragma unroll
    for (int i = 0; i < 4; ++i) {
        const int r = row0 + ty * 4 + i;
        if (r >= M) continue;
#pragma unroll
        for (int j = 0; j < 4; ++j) {
            const int c = col0 + tx * 4 + j;
            if (c >= N) continue;
            float v = acc[i][j];
            if (mode == 1) {
                v += bias[c];
                v = (v > 20.f) ? v : log1pf(__expf(v));   // softplus
            }
            C[(size_t)r * ldc + c] = v;
        }
    }
}

// ---------------------------------------------------------------------------
// Chain-tree selective scan.
// 16 lanes (= states) per (b,d) sequence; 4096 sequences.
// fwd:  h_t = dA_t*h_{t-1} + u_t          (includes u_t)
// bwd:  g_t = u_t + dA_{t+1}*g_{t+1}      (includes u_t)
// feature = (fwd + bwd - u) * 1.3 ;  y = sum_n feature*C
// fwd pass parks sum_n fwd*C in scan_out; bwd pass finalizes:
// scan_out[b,t,d] = (1.3*(ypart + sum_n (g-u)*C) + hidden*D) * silu(gate)
// ---------------------------------------------------------------------------
__global__ __launch_bounds__(256)
void scan_kernel(const float* __restrict__ proj,    // (B*L, 4096) hidden|gate
                 const float* __restrict__ ssm,     // (B*L, 96)   dt|B|C
                 const float* __restrict__ dtbuf,   // (B*L, 2048) softplus'd dt
                 const float* __restrict__ A_log,   // (2048,16)
                 const float* __restrict__ Dvec,    // (2048,)
                 float* __restrict__ scan_out,      // (B*L, 2048)
                 int B, int L)
{
    const int DI = 2048;
    const int tid = blockIdx.x * blockDim.x + threadIdx.x;
    const int n = tid & 15;
    const int p = tid >> 4;          // sequence index 0..B*DI-1
    const int b = p >> 11;           // p / 2048
    const int d = p & 2047;

    const float Aval = -__expf(A_log[d * 16 + n]);   // = -(n+1) analytically
    const float Dd = Dvec[d];
    const size_t base = (size_t)b * L;

    // ---- forward scan ----
    float h = 0.f;
    for (int t = 0; t < L; ++t) {
        const size_t row = base + t;
        const float dtv = dtbuf[row * DI + d];
        const float hv  = proj[row * 4096 + d];
        const float Bv  = ssm[row * 96 + 64 + n];
        const float Cv  = ssm[row * 96 + 80 + n];
        const float dA  = __expf(Aval * dtv);
        const float u   = dtv * Bv * hv;
        h = fmaf(dA, h, u);
        float contrib = h * Cv;
        contrib += __shfl_xor(contrib, 1);
        contrib += __shfl_xor(contrib, 2);
        contrib += __shfl_xor(contrib, 4);
        contrib += __shfl_xor(contrib, 8);
        if (n == 0) scan_out[row * DI + d] = contrib;
    }

    // ---- backward scan + finalize ----
    float g = 0.f, dAn = 0.f;
    for (int t = L - 1; t >= 0; --t) {
        const size_t row = base + t;
        const float dtv = dtbuf[row * DI + d];
        const float hv  = proj[row * 4096 + d];
        const float Bv  = ssm[row * 96 + 64 + n];
        const float Cv  = ssm[row * 96 + 80 + n];
        const float dA  = __expf(Aval * dtv);
        const float u   = dtv * Bv * hv;
        g = fmaf(dAn, g, u);
        dAn = dA;
        float contrib = (g - u) * Cv;
        contrib += __shfl_xor(contrib, 1);
        contrib += __shfl_xor(contrib, 2);
        contrib += __shfl_xor(contrib, 4);
        contrib += __shfl_xor(contrib, 8);
        if (n == 0) {
            const float y  = (scan_out[row * DI + d] + contrib) * 1.3f;
            const float gv = proj[row * 4096 + 2048 + d];
            const float sil = gv / (1.f + __expf(-gv));
            scan_out[row * DI + d] = (y + hv * Dd) * sil;
        }
    }
}

// ---------------------------------------------------------------------------
extern "C" void kernel_launch(void* const* d_in, const int* in_sizes, int n_in,
                              void* d_out, int out_size, void* d_ws, size_t ws_size,
                              hipStream_t stream)
{
    const float* x     = (const float*)d_in[0];  // (2,1024,1024)
    const float* Win   = (const float*)d_in[1];  // (4096,1024)
    const float* Wx    = (const float*)d_in[2];  // (96,2048)
    const float* Wdt   = (const float*)d_in[3];  // (2048,64)
    const float* bdt   = (const float*)d_in[4];  // (2048,)
    const float* A_log = (const float*)d_in[5];  // (2048,16)
    const float* Dv    = (const float*)d_in[6];  // (2048,)
    const float* Wout  = (const float*)d_in[7];  // (1024,2048)
    float* out = (float*)d_out;                  // (2,1024,1024)

    const int B = 2, L = 1024, DM = 1024, DI = 2048;
    const int M = B * L;                         // 2048

    // workspace layout (floats): proj | ssm | dtbuf | scan_out  (~65 MB)
    float* proj = (float*)d_ws;                      // M x 4096
    float* ssm  = proj + (size_t)M * 2 * DI;         // M x 96
    float* dtb  = ssm  + (size_t)M * 96;             // M x 2048
    float* so   = dtb  + (size_t)M * DI;             // M x 2048

    dim3 blk(256);

    // 1) proj = x @ Win^T        (2048 x 4096, K=1024)
    gemm_nt<<<dim3((2 * DI) / BN, M / BM), blk, 0, stream>>>(
        x, DM, Win, DM, proj, 2 * DI, M, 2 * DI, DM, nullptr, 0);

    // 2) ssm = hidden @ Wx^T     (2048 x 96, K=2048); hidden = proj[:, :2048]
    gemm_nt<<<dim3((96 + BN - 1) / BN, M / BM), blk, 0, stream>>>(
        proj, 2 * DI, Wx, DI, ssm, 96, M, 96, DI, nullptr, 0);

    // 3) dtb = softplus(ssm[:, :64] @ Wdt^T + bdt)   (2048 x 2048, K=64)
    gemm_nt<<<dim3(DI / BN, M / BM), blk, 0, stream>>>(
        ssm, 96, Wdt, 64, dtb, DI, M, DI, 64, bdt, 1);

    // 4) selective scan (fwd + bwd) -> so (2048 x 2048)
    scan_kernel<<<dim3((B * DI * 16) / 256), blk, 0, stream>>>(
        proj, ssm, dtb, A_log, Dv, so, B, L);

    // 5) out = so @ Wout^T       (2048 x 1024, K=2048)
    gemm_nt<<<dim3(DM / BN, M / BM), blk, 0, stream>>>(
        so, DI, Wout, DI, out, DM, M, DM, DI, nullptr, 0);
}

// Round 2
// 688.508 us; speedup vs baseline: 2.5670x; 2.5670x over previous
//
#include <hip/hip_runtime.h>
#include <cstdint>
#include <cstddef>

// ---------------------------------------------------------------------------
// Generic NT GEMM: C[M,N] = A[M,K] @ W[N,K]^T  (both row-major, K contiguous)
// mode 0: plain store.  mode 1: C = softplus(acc + bias[n])
// ---------------------------------------------------------------------------
#define BM 64
#define BN 64
#define BK 16
#define BMP 68
#define BNP 68

__global__ __launch_bounds__(256)
void gemm_nt(const float* __restrict__ A, int lda,
             const float* __restrict__ W, int ldw,
             float* __restrict__ C, int ldc,
             int M, int N, int K,
             const float* __restrict__ bias, int mode)
{
    __shared__ float As[BK][BMP];
    __shared__ float Ws[BK][BNP];

    const int tid  = threadIdx.x;
    const int row0 = blockIdx.y * BM;
    const int col0 = blockIdx.x * BN;
    const int lr = tid >> 2;
    const int lk = (tid & 3) << 2;
    const int tx = tid & 15;
    const int ty = tid >> 4;

    float acc[4][4];
#pragma unroll
    for (int i = 0; i < 4; ++i)
#pragma unroll
        for (int j = 0; j < 4; ++j) acc[i][j] = 0.f;

    for (int k0 = 0; k0 < K; k0 += BK) {
        float4 av = make_float4(0.f, 0.f, 0.f, 0.f);
        float4 wv = make_float4(0.f, 0.f, 0.f, 0.f);
        const int ar = row0 + lr;
        if (ar < M) av = *(const float4*)(A + (size_t)ar * lda + k0 + lk);
        const int wr = col0 + lr;
        if (wr < N) wv = *(const float4*)(W + (size_t)wr * ldw + k0 + lk);

        As[lk + 0][lr] = av.x; As[lk + 1][lr] = av.y;
        As[lk + 2][lr] = av.z; As[lk + 3][lr] = av.w;
        Ws[lk + 0][lr] = wv.x; Ws[lk + 1][lr] = wv.y;
        Ws[lk + 2][lr] = wv.z; Ws[lk + 3][lr] = wv.w;
        __syncthreads();

#pragma unroll
        for (int kk = 0; kk < BK; ++kk) {
            float4 a = *(const float4*)&As[kk][ty * 4];
            float4 w = *(const float4*)&Ws[kk][tx * 4];
            float ai[4] = {a.x, a.y, a.z, a.w};
            float wj[4] = {w.x, w.y, w.z, w.w};
#pragma unroll
            for (int i = 0; i < 4; ++i)
#pragma unroll
                for (int j = 0; j < 4; ++j)
                    acc[i][j] = fmaf(ai[i], wj[j], acc[i][j]);
        }
        __syncthreads();
    }

#pragma unroll
    for (int i = 0; i < 4; ++i) {
        const int r = row0 + ty * 4 + i;
        if (r >= M) continue;
#pragma unroll
        for (int j = 0; j < 4; ++j) {
            const int c = col0 + tx * 4 + j;
            if (c >= N) continue;
            float v = acc[i][j];
            if (mode == 1) {
                v += bias[c];
                v = (v > 20.f) ? v : log1pf(__expf(v));
            }
            C[(size_t)r * ldc + c] = v;
        }
    }
}

// ---------------------------------------------------------------------------
// Chunked parallel scan.  thread <-> (b, d, chunk); d fastest => coalesced.
// fwd:  h_t = dA_t*h_{t-1} + u_t
// bwd:  g_t = dA_{t+1}*g_{t+1} + u_t   (dA_L = 0)
// out[b,t,d] = (1.3*sum_n (h+g-u)*C + hidden*D) * silu(gate)
// ---------------------------------------------------------------------------
#define NC 32          // chunks per sequence
#define CL 32          // chunk length (NC*CL == L == 1024)
#define DI 2048
#define NST 16

// S1: chunk-local scans.  Writes Pf/He (fwd prod, fwd end state),
// Pb/Gs (bwd prod, bwd start state), dtbound (dt at t0+CL, +inf at seq end).
__global__ __launch_bounds__(256)
void scan_chunk_local(const float* __restrict__ proj,
                      const float* __restrict__ ssm,
                      const float* __restrict__ dtb,
                      const float* __restrict__ A_log,
                      float* __restrict__ Pf, float* __restrict__ He,
                      float* __restrict__ Pb, float* __restrict__ Gs,
                      float* __restrict__ dtbound)
{
    const int g = blockIdx.x * 256 + threadIdx.x;
    const int d = g & (DI - 1);
    const int r = g >> 11;
    const int c = r & (NC - 1);
    const int b = r >> 5;
    const int t0 = c * CL;
    const size_t rowbase = (size_t)b * 1024;

    float Av[NST];
#pragma unroll
    for (int n = 0; n < NST; ++n) Av[n] = -__expf(A_log[d * NST + n]);

    // ---- forward locals ----
    float h[NST], pf[NST];
#pragma unroll
    for (int n = 0; n < NST; ++n) { h[n] = 0.f; pf[n] = 1.f; }
    for (int t = t0; t < t0 + CL; ++t) {
        const size_t row = rowbase + t;
        const float dtv = dtb[row * DI + d];
        const float hv  = proj[row * 4096 + d];
        const float dh  = dtv * hv;
#pragma unroll
        for (int n = 0; n < NST; ++n) {
            const float Bv = ssm[row * 96 + 64 + n];
            const float dA = __expf(Av[n] * dtv);
            h[n] = fmaf(dA, h[n], dh * Bv);
            pf[n] *= dA;
        }
    }
    const size_t ibase = ((size_t)((b * NC + c) * NST) << 11) + d;
#pragma unroll
    for (int n = 0; n < NST; ++n) {
        Pf[ibase + ((size_t)n << 11)] = pf[n];
        He[ibase + ((size_t)n << 11)] = h[n];
    }

    // ---- backward locals ----
    float dtn = INFINITY;                    // exp(Av*inf) = 0 kills the tail
    const int t1 = t0 + CL;
    if (t1 < 1024) dtn = dtb[(rowbase + t1) * DI + d];
    dtbound[(size_t)(b * NC + c) * DI + d] = dtn;

    float gq[NST], pb[NST], dan[NST];
#pragma unroll
    for (int n = 0; n < NST; ++n) {
        gq[n] = 0.f; pb[n] = 1.f;
        dan[n] = __expf(Av[n] * dtn);
    }
    for (int t = t0 + CL - 1; t >= t0; --t) {
        const size_t row = rowbase + t;
        const float dtv = dtb[row * DI + d];
        const float hv  = proj[row * 4096 + d];
        const float dh  = dtv * hv;
#pragma unroll
        for (int n = 0; n < NST; ++n) {
            const float Bv = ssm[row * 96 + 64 + n];
            gq[n] = fmaf(dan[n], gq[n], dh * Bv);
            pb[n] *= dan[n];
            dan[n] = __expf(Av[n] * dtv);
        }
    }
#pragma unroll
    for (int n = 0; n < NST; ++n) {
        Pb[ibase + ((size_t)n << 11)] = pb[n];
        Gs[ibase + ((size_t)n << 11)] = gq[n];
    }
}

// S2: scan across chunks.  In-place: He <- Hstart, Gs <- Gtail.
__global__ __launch_bounds__(256)
void scan_combine(const float* __restrict__ Pf, float* __restrict__ He,
                  const float* __restrict__ Pb, float* __restrict__ Gs)
{
    const int g = blockIdx.x * 256 + threadIdx.x;
    const int d = g & (DI - 1);
    const int r = g >> 11;
    const int n = r & (NST - 1);
    const int b = r >> 4;
    const size_t base = ((size_t)(b * NC * NST + n) << 11) + d;
    const size_t cstride = (size_t)NST << 11;

    float H = 0.f;
    for (int c = 0; c < NC; ++c) {
        const size_t i = base + (size_t)c * cstride;
        const float p = Pf[i], e = He[i];
        He[i] = H;                 // Hstart(c) = H(c-1)
        H = fmaf(p, H, e);
    }
    float G = 0.f;
    for (int c = NC - 1; c >= 0; --c) {
        const size_t i = base + (size_t)c * cstride;
        const float p = Pb[i], s = Gs[i];
        Gs[i] = G;                 // Gtail(c) = T_c
        G = fmaf(p, G, s);
    }
}

// S3: apply.  fwd re-scan -> y per t in LDS; bwd re-scan finalizes and
// overwrites dtb with the gated scan output (safe: only this thread touches
// (row in chunk, d), and dt[row] is consumed before the write).
__global__ __launch_bounds__(256)
void scan_apply(const float* __restrict__ proj,
                const float* __restrict__ ssm,
                float* __restrict__ dtb,
                const float* __restrict__ A_log,
                const float* __restrict__ Dvec,
                const float* __restrict__ He,   // = Hstart
                const float* __restrict__ Gs,   // = Gtail
                const float* __restrict__ dtbound)
{
    __shared__ float ybuf[256][CL + 1];
    const int tid = threadIdx.x;
    const int g = blockIdx.x * 256 + tid;
    const int d = g & (DI - 1);
    const int r = g >> 11;
    const int c = r & (NC - 1);
    const int b = r >> 5;
    const int t0 = c * CL;
    const size_t rowbase = (size_t)b * 1024;

    float Av[NST];
#pragma unroll
    for (int n = 0; n < NST; ++n) Av[n] = -__expf(A_log[d * NST + n]);
    const size_t ibase = ((size_t)((b * NC + c) * NST) << 11) + d;

    // ---- forward apply ----
    float h[NST];
#pragma unroll
    for (int n = 0; n < NST; ++n) h[n] = He[ibase + ((size_t)n << 11)];
    for (int t = t0; t < t0 + CL; ++t) {
        const size_t row = rowbase + t;
        const float dtv = dtb[row * DI + d];
        const float hv  = proj[row * 4096 + d];
        const float dh  = dtv * hv;
        float y = 0.f;
#pragma unroll
        for (int n = 0; n < NST; ++n) {
            const float Bv = ssm[row * 96 + 64 + n];
            const float Cv = ssm[row * 96 + 80 + n];
            const float dA = __expf(Av[n] * dtv);
            h[n] = fmaf(dA, h[n], dh * Bv);
            y = fmaf(h[n], Cv, y);
        }
        ybuf[tid][t - t0] = y;
    }

    // ---- backward apply + finalize ----
    float gq[NST], dan[NST];
#pragma unroll
    for (int n = 0; n < NST; ++n) gq[n] = Gs[ibase + ((size_t)n << 11)];
    {
        const float dtn = dtbound[(size_t)(b * NC + c) * DI + d];
#pragma unroll
        for (int n = 0; n < NST; ++n) dan[n] = __expf(Av[n] * dtn);
    }
    const float Dd = Dvec[d];
    for (int t = t0 + CL - 1; t >= t0; --t) {
        const size_t row = rowbase + t;
        const float dtv = dtb[row * DI + d];
        const float hv  = proj[row * 4096 + d];
        const float dh  = dtv * hv;
        float acc = 0.f;
#pragma unroll
        for (int n = 0; n < NST; ++n) {
            const float Bv = ssm[row * 96 + 64 + n];
            const float Cv = ssm[row * 96 + 80 + n];
            const float u  = dh * Bv;
            gq[n] = fmaf(dan[n], gq[n], u);
            dan[n] = __expf(Av[n] * dtv);
            acc = fmaf(gq[n] - u, Cv, acc);
        }
        const float y   = (ybuf[tid][t - t0] + acc) * 1.3f;
        const float gv  = proj[row * 4096 + DI + d];
        const float sil = gv / (1.f + __expf(-gv));
        dtb[row * DI + d] = (y + hv * Dd) * sil;   // overlay: dt -> scan_out
    }
}

// ---------------------------------------------------------------------------
extern "C" void kernel_launch(void* const* d_in, const int* in_sizes, int n_in,
                              void* d_out, int out_size, void* d_ws, size_t ws_size,
                              hipStream_t stream)
{
    const float* x     = (const float*)d_in[0];
    const float* Win   = (const float*)d_in[1];
    const float* Wx    = (const float*)d_in[2];
    const float* Wdt   = (const float*)d_in[3];
    const float* bdt   = (const float*)d_in[4];
    const float* A_log = (const float*)d_in[5];
    const float* Dv    = (const float*)d_in[6];
    const float* Wout  = (const float*)d_in[7];
    float* out = (float*)d_out;

    const int B = 2, L = 1024, DM = 1024;
    const int M = B * L;                         // 2048

    // ws layout (floats): proj | ssm | dtb(=scan_out) | Pf | He | Pb | Gs | dtbound
    float* proj = (float*)d_ws;                      // M x 4096
    float* ssm  = proj + (size_t)M * 2 * DI;         // M x 96
    float* dtb  = ssm  + (size_t)M * 96;             // M x 2048
    float* Pf   = dtb  + (size_t)M * DI;             // 2*NC*16*2048 each
    float* He   = Pf   + (size_t)B * NC * NST * DI;
    float* Pb   = He   + (size_t)B * NC * NST * DI;
    float* Gs   = Pb   + (size_t)B * NC * NST * DI;
    float* dtbd = Gs   + (size_t)B * NC * NST * DI;  // B*NC*2048

    dim3 blk(256);

    // 1) proj = x @ Win^T
    gemm_nt<<<dim3((2 * DI) / BN, M / BM), blk, 0, stream>>>(
        x, DM, Win, DM, proj, 2 * DI, M, 2 * DI, DM, nullptr, 0);

    // 2) ssm = hidden @ Wx^T
    gemm_nt<<<dim3((96 + BN - 1) / BN, M / BM), blk, 0, stream>>>(
        proj, 2 * DI, Wx, DI, ssm, 96, M, 96, DI, nullptr, 0);

    // 3) dtb = softplus(ssm[:, :64] @ Wdt^T + bdt)
    gemm_nt<<<dim3(DI / BN, M / BM), blk, 0, stream>>>(
        ssm, 96, Wdt, 64, dtb, DI, M, DI, 64, bdt, 1);

    // 4) scan: chunk locals -> combine -> apply (output overlays dtb)
    scan_chunk_local<<<dim3((B * DI * NC) / 256), blk, 0, stream>>>(
        proj, ssm, dtb, A_log, Pf, He, Pb, Gs, dtbd);
    scan_combine<<<dim3((B * DI * NST) / 256), blk, 0, stream>>>(Pf, He, Pb, Gs);
    scan_apply<<<dim3((B * DI * NC) / 256), blk, 0, stream>>>(
        proj, ssm, dtb, A_log, Dv, He, Gs, dtbd);

    // 5) out = scan_out @ Wout^T
    gemm_nt<<<dim3(DM / BN, M / BM), blk, 0, stream>>>(
        dtb, DI, Wout, DI, out, DM, M, DM, DI, nullptr, 0);
}

// Round 5
// 396.644 us; speedup vs baseline: 4.4559x; 1.7358x over previous
//
#include <hip/hip_runtime.h>
#include <hip/hip_bf16.h>
#include <cstdint>
#include <cstddef>

typedef __hip_bfloat16 bf16;
typedef __attribute__((ext_vector_type(8))) short short8v;
typedef __attribute__((ext_vector_type(4))) float f32x4;

// ---------------------------------------------------------------------------
// f32 -> bf16 cast, float4 in / ushort4 out
// ---------------------------------------------------------------------------
__global__ __launch_bounds__(256)
void cast_bf16(const float* __restrict__ in, ushort* __restrict__ out, int n4)
{
    const int i = blockIdx.x * 256 + threadIdx.x;
    if (i >= n4) return;
    const float4 v = ((const float4*)in)[i];
    ushort4 o;
    bf16 h;
    h = __float2bfloat16(v.x); o.x = *(ushort*)&h;
    h = __float2bfloat16(v.y); o.y = *(ushort*)&h;
    h = __float2bfloat16(v.z); o.z = *(ushort*)&h;
    h = __float2bfloat16(v.w); o.w = *(ushort*)&h;
    ((ushort4*)out)[i] = o;
}

// ---------------------------------------------------------------------------
// bf16 MFMA NT GEMM: C[M,N](f32) = A[M,K] @ W[N,K]^T, both bf16 row-major.
// 128x128 tile, BK=32, 256 thr = 4 waves (2x2), 4x4 16x16x32 frags per wave.
// M, N multiples of 128; K multiple of 32.  (m97 structure)
// ---------------------------------------------------------------------------
__global__ __launch_bounds__(256)
void gemm_bf16_mfma(const bf16* __restrict__ A, int lda,
                    const bf16* __restrict__ W, int ldw,
                    float* __restrict__ C, int ldc, int K)
{
    __shared__ short Asl[128 * 32];
    __shared__ short Wsl[128 * 32];
    const int tid = threadIdx.x;
    const int lane = tid & 63, wave = tid >> 6;
    const int row0 = blockIdx.y * 128, col0 = blockIdx.x * 128;
    const int wr = wave >> 1, wc = wave & 1;
    const int lr = lane & 15, lq = lane >> 4;

    f32x4 acc[4][4] = {};

    for (int k0 = 0; k0 < K; k0 += 32) {
#pragma unroll
        for (int i = 0; i < 2; ++i) {
            const int o = ((i * 4 + wave) << 9) + lane * 8;  // element offset in tile
            const int r = o >> 5, kk = o & 31;
            __builtin_amdgcn_global_load_lds(
                (const __attribute__((address_space(1))) void*)(A + (size_t)(row0 + r) * lda + k0 + kk),
                (__attribute__((address_space(3))) void*)(Asl + (((i * 4 + wave) << 9))),
                16, 0, 0);
            __builtin_amdgcn_global_load_lds(
                (const __attribute__((address_space(1))) void*)(W + (size_t)(col0 + r) * ldw + k0 + kk),
                (__attribute__((address_space(3))) void*)(Wsl + (((i * 4 + wave) << 9))),
                16, 0, 0);
        }
        __syncthreads();

        short8v af[4], wf[4];
#pragma unroll
        for (int m = 0; m < 4; ++m)
            af[m] = *(const short8v*)&Asl[(wr * 64 + m * 16 + lr) * 32 + lq * 8];
#pragma unroll
        for (int n = 0; n < 4; ++n)
            wf[n] = *(const short8v*)&Wsl[(wc * 64 + n * 16 + lr) * 32 + lq * 8];
#pragma unroll
        for (int m = 0; m < 4; ++m)
#pragma unroll
            for (int n = 0; n < 4; ++n)
                acc[m][n] = __builtin_amdgcn_mfma_f32_16x16x32_bf16(af[m], wf[n], acc[m][n], 0, 0, 0);
        __syncthreads();
    }

#pragma unroll
    for (int m = 0; m < 4; ++m) {
        const int r = row0 + wr * 64 + m * 16 + lq * 4;
#pragma unroll
        for (int n = 0; n < 4; ++n) {
            const int c = col0 + wc * 64 + n * 16 + lr;
#pragma unroll
            for (int j = 0; j < 4; ++j)
                C[(size_t)(r + j) * ldc + c] = acc[m][n][j];
        }
    }
}

// ---------------------------------------------------------------------------
// f32 NT GEMM (small shapes): C = A @ W^T.  mode 1: softplus(acc+bias)
// ---------------------------------------------------------------------------
#define BM 64
#define BN 64
#define BK 16
#define BMP 68
#define BNP 68

__global__ __launch_bounds__(256)
void gemm_nt(const float* __restrict__ A, int lda,
             const float* __restrict__ W, int ldw,
             float* __restrict__ C, int ldc,
             int M, int N, int K,
             const float* __restrict__ bias, int mode)
{
    __shared__ float As[BK][BMP];
    __shared__ float Ws[BK][BNP];

    const int tid  = threadIdx.x;
    const int row0 = blockIdx.y * BM;
    const int col0 = blockIdx.x * BN;
    const int lr = tid >> 2;
    const int lk = (tid & 3) << 2;
    const int tx = tid & 15;
    const int ty = tid >> 4;

    float acc[4][4];
#pragma unroll
    for (int i = 0; i < 4; ++i)
#pragma unroll
        for (int j = 0; j < 4; ++j) acc[i][j] = 0.f;

    for (int k0 = 0; k0 < K; k0 += BK) {
        float4 av = make_float4(0.f, 0.f, 0.f, 0.f);
        float4 wv = make_float4(0.f, 0.f, 0.f, 0.f);
        const int ar = row0 + lr;
        if (ar < M) av = *(const float4*)(A + (size_t)ar * lda + k0 + lk);
        const int wr = col0 + lr;
        if (wr < N) wv = *(const float4*)(W + (size_t)wr * ldw + k0 + lk);

        As[lk + 0][lr] = av.x; As[lk + 1][lr] = av.y;
        As[lk + 2][lr] = av.z; As[lk + 3][lr] = av.w;
        Ws[lk + 0][lr] = wv.x; Ws[lk + 1][lr] = wv.y;
        Ws[lk + 2][lr] = wv.z; Ws[lk + 3][lr] = wv.w;
        __syncthreads();

#pragma unroll
        for (int kk = 0; kk < BK; ++kk) {
            float4 a = *(const float4*)&As[kk][ty * 4];
            float4 w = *(const float4*)&Ws[kk][tx * 4];
            float ai[4] = {a.x, a.y, a.z, a.w};
            float wj[4] = {w.x, w.y, w.z, w.w};
#pragma unroll
            for (int i = 0; i < 4; ++i)
#pragma unroll
                for (int j = 0; j < 4; ++j)
                    acc[i][j] = fmaf(ai[i], wj[j], acc[i][j]);
        }
        __syncthreads();
    }

#pragma unroll
    for (int i = 0; i < 4; ++i) {
        const int r = row0 + ty * 4 + i;
        if (r >= M) continue;
#pragma unroll
        for (int j = 0; j < 4; ++j) {
            const int c = col0 + tx * 4 + j;
            if (c >= N) continue;
            float v = acc[i][j];
            if (mode == 1) {
                v += bias[c];
                v = (v > 20.f) ? v : log1pf(__expf(v));
            }
            C[(size_t)r * ldc + c] = v;
        }
    }
}

// ---------------------------------------------------------------------------
// Chunked parallel scan (unchanged structure from round 2).
// ---------------------------------------------------------------------------
#define NC 32
#define CL 32
#define DI 2048
#define NST 16

__global__ __launch_bounds__(256)
void scan_chunk_local(const float* __restrict__ proj,
                      const float* __restrict__ ssm,
                      const float* __restrict__ dtb,
                      const float* __restrict__ A_log,
                      float* __restrict__ Pf, float* __restrict__ He,
                      float* __restrict__ Pb, float* __restrict__ Gs,
                      float* __restrict__ dtbound)
{
    const int g = blockIdx.x * 256 + threadIdx.x;
    const int d = g & (DI - 1);
    const int r = g >> 11;
    const int c = r & (NC - 1);
    const int b = r >> 5;
    const int t0 = c * CL;
    const size_t rowbase = (size_t)b * 1024;

    float Av[NST];
#pragma unroll
    for (int n = 0; n < NST; ++n) Av[n] = -__expf(A_log[d * NST + n]);

    float h[NST], pf[NST];
#pragma unroll
    for (int n = 0; n < NST; ++n) { h[n] = 0.f; pf[n] = 1.f; }
    for (int t = t0; t < t0 + CL; ++t) {
        const size_t row = rowbase + t;
        const float dtv = dtb[row * DI + d];
        const float hv  = proj[row * 4096 + d];
        const float dh  = dtv * hv;
#pragma unroll
        for (int n = 0; n < NST; ++n) {
            const float Bv = ssm[row * 96 + 64 + n];
            const float dA = __expf(Av[n] * dtv);
            h[n] = fmaf(dA, h[n], dh * Bv);
            pf[n] *= dA;
        }
    }
    const size_t ibase = ((size_t)((b * NC + c) * NST) << 11) + d;
#pragma unroll
    for (int n = 0; n < NST; ++n) {
        Pf[ibase + ((size_t)n << 11)] = pf[n];
        He[ibase + ((size_t)n << 11)] = h[n];
    }

    float dtn = INFINITY;
    const int t1 = t0 + CL;
    if (t1 < 1024) dtn = dtb[(rowbase + t1) * DI + d];
    dtbound[(size_t)(b * NC + c) * DI + d] = dtn;

    float gq[NST], pb[NST], dan[NST];
#pragma unroll
    for (int n = 0; n < NST; ++n) {
        gq[n] = 0.f; pb[n] = 1.f;
        dan[n] = __expf(Av[n] * dtn);
    }
    for (int t = t0 + CL - 1; t >= t0; --t) {
        const size_t row = rowbase + t;
        const float dtv = dtb[row * DI + d];
        const float hv  = proj[row * 4096 + d];
        const float dh  = dtv * hv;
#pragma unroll
        for (int n = 0; n < NST; ++n) {
            const float Bv = ssm[row * 96 + 64 + n];
            gq[n] = fmaf(dan[n], gq[n], dh * Bv);
            pb[n] *= dan[n];
            dan[n] = __expf(Av[n] * dtv);
        }
    }
#pragma unroll
    for (int n = 0; n < NST; ++n) {
        Pb[ibase + ((size_t)n << 11)] = pb[n];
        Gs[ibase + ((size_t)n << 11)] = gq[n];
    }
}

__global__ __launch_bounds__(256)
void scan_combine(const float* __restrict__ Pf, float* __restrict__ He,
                  const float* __restrict__ Pb, float* __restrict__ Gs)
{
    const int g = blockIdx.x * 256 + threadIdx.x;
    const int d = g & (DI - 1);
    const int r = g >> 11;
    const int n = r & (NST - 1);
    const int b = r >> 4;
    const size_t base = ((size_t)(b * NC * NST + n) << 11) + d;
    const size_t cstride = (size_t)NST << 11;

    float H = 0.f;
    for (int c = 0; c < NC; ++c) {
        const size_t i = base + (size_t)c * cstride;
        const float p = Pf[i], e = He[i];
        He[i] = H;
        H = fmaf(p, H, e);
    }
    float G = 0.f;
    for (int c = NC - 1; c >= 0; --c) {
        const size_t i = base + (size_t)c * cstride;
        const float p = Pb[i], s = Gs[i];
        Gs[i] = G;
        G = fmaf(p, G, s);
    }
}

// S3: apply; writes gated scan output as bf16 (feeds the MFMA out-proj).
__global__ __launch_bounds__(256)
void scan_apply(const float* __restrict__ proj,
                const float* __restrict__ ssm,
                const float* __restrict__ dtb,
                const float* __restrict__ A_log,
                const float* __restrict__ Dvec,
                const float* __restrict__ He,
                const float* __restrict__ Gs,
                const float* __restrict__ dtbound,
                ushort* __restrict__ sob)
{
    __shared__ float ybuf[256][CL + 1];
    const int tid = threadIdx.x;
    const int g = blockIdx.x * 256 + tid;
    const int d = g & (DI - 1);
    const int r = g >> 11;
    const int c = r & (NC - 1);
    const int b = r >> 5;
    const int t0 = c * CL;
    const size_t rowbase = (size_t)b * 1024;

    float Av[NST];
#pragma unroll
    for (int n = 0; n < NST; ++n) Av[n] = -__expf(A_log[d * NST + n]);
    const size_t ibase = ((size_t)((b * NC + c) * NST) << 11) + d;

    float h[NST];
#pragma unroll
    for (int n = 0; n < NST; ++n) h[n] = He[ibase + ((size_t)n << 11)];
    for (int t = t0; t < t0 + CL; ++t) {
        const size_t row = rowbase + t;
        const float dtv = dtb[row * DI + d];
        const float hv  = proj[row * 4096 + d];
        const float dh  = dtv * hv;
        float y = 0.f;
#pragma unroll
        for (int n = 0; n < NST; ++n) {
            const float Bv = ssm[row * 96 + 64 + n];
            const float Cv = ssm[row * 96 + 80 + n];
            const float dA = __expf(Av[n] * dtv);
            h[n] = fmaf(dA, h[n], dh * Bv);
            y = fmaf(h[n], Cv, y);
        }
        ybuf[tid][t - t0] = y;
    }

    float gq[NST], dan[NST];
#pragma unroll
    for (int n = 0; n < NST; ++n) gq[n] = Gs[ibase + ((size_t)n << 11)];
    {
        const float dtn = dtbound[(size_t)(b * NC + c) * DI + d];
#pragma unroll
        for (int n = 0; n < NST; ++n) dan[n] = __expf(Av[n] * dtn);
    }
    const float Dd = Dvec[d];
    for (int t = t0 + CL - 1; t >= t0; --t) {
        const size_t row = rowbase + t;
        const float dtv = dtb[row * DI + d];
        const float hv  = proj[row * 4096 + d];
        const float dh  = dtv * hv;
        float acc = 0.f;
#pragma unroll
        for (int n = 0; n < NST; ++n) {
            const float Bv = ssm[row * 96 + 64 + n];
            const float Cv = ssm[row * 96 + 80 + n];
            const float u  = dh * Bv;
            gq[n] = fmaf(dan[n], gq[n], u);
            dan[n] = __expf(Av[n] * dtv);
            acc = fmaf(gq[n] - u, Cv, acc);
        }
        const float y   = (ybuf[tid][t - t0] + acc) * 1.3f;
        const float gv  = proj[row * 4096 + DI + d];
        const float sil = gv / (1.f + __expf(-gv));
        const float val = (y + hv * Dd) * sil;
        bf16 hb = __float2bfloat16(val);
        sob[row * DI + d] = *(ushort*)&hb;
    }
}

// ---------------------------------------------------------------------------
extern "C" void kernel_launch(void* const* d_in, const int* in_sizes, int n_in,
                              void* d_out, int out_size, void* d_ws, size_t ws_size,
                              hipStream_t stream)
{
    const float* x     = (const float*)d_in[0];
    const float* Win   = (const float*)d_in[1];
    const float* Wx    = (const float*)d_in[2];
    const float* Wdt   = (const float*)d_in[3];
    const float* bdt   = (const float*)d_in[4];
    const float* A_log = (const float*)d_in[5];
    const float* Dv    = (const float*)d_in[6];
    const float* Wout  = (const float*)d_in[7];
    float* out = (float*)d_out;

    const int B = 2, L = 1024, DM = 1024;
    const int M = B * L;                          // 2048

    // ws layout (float units)
    float* proj = (float*)d_ws;                       // M x 4096
    float* ssm  = proj + (size_t)M * 2 * DI;          // M x 96
    float* dtb  = ssm  + (size_t)M * 96;              // M x 2048
    float* Pf   = dtb  + (size_t)M * DI;
    float* He   = Pf   + (size_t)B * NC * NST * DI;
    float* Pb   = He   + (size_t)B * NC * NST * DI;
    float* Gs   = Pb   + (size_t)B * NC * NST * DI;
    float* dtbd = Gs   + (size_t)B * NC * NST * DI;   // B*NC*2048
    ushort* xb    = (ushort*)(dtbd + (size_t)B * NC * DI);  // M x 1024 bf16
    ushort* Winb  = xb    + (size_t)M * DM;           // 4096 x 1024 bf16
    ushort* Woutb = Winb  + (size_t)(2 * DI) * DM;    // 1024 x 2048 bf16
    ushort* sob   = Woutb + (size_t)DM * DI;          // M x 2048 bf16

    dim3 blk(256);

    // casts
    cast_bf16<<<dim3((M * DM / 4) / 256), blk, 0, stream>>>(x, xb, M * DM / 4);
    cast_bf16<<<dim3((2 * DI * DM / 4) / 256), blk, 0, stream>>>(Win, Winb, 2 * DI * DM / 4);
    cast_bf16<<<dim3((DM * DI / 4) / 256), blk, 0, stream>>>(Wout, Woutb, DM * DI / 4);

    // 1) proj = x @ Win^T   (MFMA bf16, 2048x4096, K=1024)
    gemm_bf16_mfma<<<dim3((2 * DI) / 128, M / 128), blk, 0, stream>>>(
        (const bf16*)xb, DM, (const bf16*)Winb, DM, proj, 2 * DI, DM);

    // 2) ssm = hidden @ Wx^T  (f32, 2048x96, K=2048)
    gemm_nt<<<dim3((96 + BN - 1) / BN, M / BM), blk, 0, stream>>>(
        proj, 2 * DI, Wx, DI, ssm, 96, M, 96, DI, nullptr, 0);

    // 3) dtb = softplus(ssm[:, :64] @ Wdt^T + bdt)  (f32, 2048x2048, K=64)
    gemm_nt<<<dim3(DI / BN, M / BM), blk, 0, stream>>>(
        ssm, 96, Wdt, 64, dtb, DI, M, DI, 64, bdt, 1);

    // 4) scan
    scan_chunk_local<<<dim3((B * DI * NC) / 256), blk, 0, stream>>>(
        proj, ssm, dtb, A_log, Pf, He, Pb, Gs, dtbd);
    scan_combine<<<dim3((B * DI * NST) / 256), blk, 0, stream>>>(Pf, He, Pb, Gs);
    scan_apply<<<dim3((B * DI * NC) / 256), blk, 0, stream>>>(
        proj, ssm, dtb, A_log, Dv, He, Gs, dtbd, sob);

    // 5) out = scan_out @ Wout^T  (MFMA bf16, 2048x1024, K=2048)
    gemm_bf16_mfma<<<dim3(DM / 128, M / 128), blk, 0, stream>>>(
        (const bf16*)sob, DI, (const bf16*)Woutb, DI, out, DM, DI);
}

// Round 6
// 315.033 us; speedup vs baseline: 5.6103x; 1.2591x over previous
//
#include <hip/hip_runtime.h>
#include <hip/hip_bf16.h>
#include <cstdint>
#include <cstddef>

typedef __hip_bfloat16 bf16;
typedef __attribute__((ext_vector_type(8))) short short8v;
typedef __attribute__((ext_vector_type(4))) float f32x4;

// ---------------------------------------------------------------------------
// f32 -> bf16 cast, float4 in / ushort4 out
// ---------------------------------------------------------------------------
__global__ __launch_bounds__(256)
void cast_bf16(const float* __restrict__ in, ushort* __restrict__ out, int n4)
{
    const int i = blockIdx.x * 256 + threadIdx.x;
    if (i >= n4) return;
    const float4 v = ((const float4*)in)[i];
    ushort4 o;
    bf16 h;
    h = __float2bfloat16(v.x); o.x = *(ushort*)&h;
    h = __float2bfloat16(v.y); o.y = *(ushort*)&h;
    h = __float2bfloat16(v.z); o.z = *(ushort*)&h;
    h = __float2bfloat16(v.w); o.w = *(ushort*)&h;
    ((ushort4*)out)[i] = o;
}

// ---------------------------------------------------------------------------
// bf16 MFMA NT GEMM: C[M,N](f32) = A[M,K] @ W[N,K]^T, both bf16 row-major.
// 128x128 tile, BK=32, 256 thr = 4 waves (2x2), 4x4 16x16x32 frags per wave.
// ---------------------------------------------------------------------------
__global__ __launch_bounds__(256)
void gemm_bf16_mfma(const bf16* __restrict__ A, int lda,
                    const bf16* __restrict__ W, int ldw,
                    float* __restrict__ C, int ldc, int K)
{
    __shared__ short Asl[128 * 32];
    __shared__ short Wsl[128 * 32];
    const int tid = threadIdx.x;
    const int lane = tid & 63, wave = tid >> 6;
    const int row0 = blockIdx.y * 128, col0 = blockIdx.x * 128;
    const int wr = wave >> 1, wc = wave & 1;
    const int lr = lane & 15, lq = lane >> 4;

    f32x4 acc[4][4] = {};

    for (int k0 = 0; k0 < K; k0 += 32) {
#pragma unroll
        for (int i = 0; i < 2; ++i) {
            const int o = ((i * 4 + wave) << 9) + lane * 8;
            const int r = o >> 5, kk = o & 31;
            __builtin_amdgcn_global_load_lds(
                (const __attribute__((address_space(1))) void*)(A + (size_t)(row0 + r) * lda + k0 + kk),
                (__attribute__((address_space(3))) void*)(Asl + (((i * 4 + wave) << 9))),
                16, 0, 0);
            __builtin_amdgcn_global_load_lds(
                (const __attribute__((address_space(1))) void*)(W + (size_t)(col0 + r) * ldw + k0 + kk),
                (__attribute__((address_space(3))) void*)(Wsl + (((i * 4 + wave) << 9))),
                16, 0, 0);
        }
        __syncthreads();

        short8v af[4], wf[4];
#pragma unroll
        for (int m = 0; m < 4; ++m)
            af[m] = *(const short8v*)&Asl[(wr * 64 + m * 16 + lr) * 32 + lq * 8];
#pragma unroll
        for (int n = 0; n < 4; ++n)
            wf[n] = *(const short8v*)&Wsl[(wc * 64 + n * 16 + lr) * 32 + lq * 8];
#pragma unroll
        for (int m = 0; m < 4; ++m)
#pragma unroll
            for (int n = 0; n < 4; ++n)
                acc[m][n] = __builtin_amdgcn_mfma_f32_16x16x32_bf16(af[m], wf[n], acc[m][n], 0, 0, 0);
        __syncthreads();
    }

#pragma unroll
    for (int m = 0; m < 4; ++m) {
        const int r = row0 + wr * 64 + m * 16 + lq * 4;
#pragma unroll
        for (int n = 0; n < 4; ++n) {
            const int c = col0 + wc * 64 + n * 16 + lr;
#pragma unroll
            for (int j = 0; j < 4; ++j)
                C[(size_t)(r + j) * ldc + c] = acc[m][n][j];
        }
    }
}

// ---------------------------------------------------------------------------
// f32 NT GEMM: C = A @ W^T.  mode 1: softplus(acc+bias)
// ---------------------------------------------------------------------------
#define BM 64
#define BN 64
#define BK 16
#define BMP 68
#define BNP 68

__global__ __launch_bounds__(256)
void gemm_nt(const float* __restrict__ A, int lda,
             const float* __restrict__ W, int ldw,
             float* __restrict__ C, int ldc,
             int M, int N, int K,
             const float* __restrict__ bias, int mode)
{
    __shared__ float As[BK][BMP];
    __shared__ float Ws[BK][BNP];

    const int tid  = threadIdx.x;
    const int row0 = blockIdx.y * BM;
    const int col0 = blockIdx.x * BN;
    const int lr = tid >> 2;
    const int lk = (tid & 3) << 2;
    const int tx = tid & 15;
    const int ty = tid >> 4;

    float acc[4][4];
#pragma unroll
    for (int i = 0; i < 4; ++i)
#pragma unroll
        for (int j = 0; j < 4; ++j) acc[i][j] = 0.f;

    for (int k0 = 0; k0 < K; k0 += BK) {
        float4 av = make_float4(0.f, 0.f, 0.f, 0.f);
        float4 wv = make_float4(0.f, 0.f, 0.f, 0.f);
        const int ar = row0 + lr;
        if (ar < M) av = *(const float4*)(A + (size_t)ar * lda + k0 + lk);
        const int wr = col0 + lr;
        if (wr < N) wv = *(const float4*)(W + (size_t)wr * ldw + k0 + lk);

        As[lk + 0][lr] = av.x; As[lk + 1][lr] = av.y;
        As[lk + 2][lr] = av.z; As[lk + 3][lr] = av.w;
        Ws[lk + 0][lr] = wv.x; Ws[lk + 1][lr] = wv.y;
        Ws[lk + 2][lr] = wv.z; Ws[lk + 3][lr] = wv.w;
        __syncthreads();

#pragma unroll
        for (int kk = 0; kk < BK; ++kk) {
            float4 a = *(const float4*)&As[kk][ty * 4];
            float4 w = *(const float4*)&Ws[kk][tx * 4];
            float ai[4] = {a.x, a.y, a.z, a.w};
            float wj[4] = {w.x, w.y, w.z, w.w};
#pragma unroll
            for (int i = 0; i < 4; ++i)
#pragma unroll
                for (int j = 0; j < 4; ++j)
                    acc[i][j] = fmaf(ai[i], wj[j], acc[i][j]);
        }
        __syncthreads();
    }

#pragma unroll
    for (int i = 0; i < 4; ++i) {
        const int r = row0 + ty * 4 + i;
        if (r >= M) continue;
#pragma unroll
        for (int j = 0; j < 4; ++j) {
            const int c = col0 + tx * 4 + j;
            if (c >= N) continue;
            float v = acc[i][j];
            if (mode == 1) {
                v += bias[c];
                v = (v > 20.f) ? v : log1pf(__expf(v));
            }
            C[(size_t)r * ldc + c] = v;
        }
    }
}

// ---------------------------------------------------------------------------
// Split-K f32 NT GEMM for tall-skinny shapes (GEMM2: 2048x96, K=2048).
// blockIdx.z = K-split; partials P[z][M][N] (ldc=N); reduce kernel sums.
// ---------------------------------------------------------------------------
__global__ __launch_bounds__(256)
void gemm_nt_splitk(const float* __restrict__ A, int lda,
                    const float* __restrict__ W, int ldw,
                    float* __restrict__ P,
                    int M, int N, int K, int ksplit)
{
    __shared__ float As[BK][BMP];
    __shared__ float Ws[BK][BNP];

    const int tid  = threadIdx.x;
    const int row0 = blockIdx.y * BM;
    const int col0 = blockIdx.x * BN;
    const int z    = blockIdx.z;
    const int k0s = z * ksplit, k0e = k0s + ksplit;
    const int lr = tid >> 2;
    const int lk = (tid & 3) << 2;
    const int tx = tid & 15;
    const int ty = tid >> 4;

    float acc[4][4];
#pragma unroll
    for (int i = 0; i < 4; ++i)
#pragma unroll
        for (int j = 0; j < 4; ++j) acc[i][j] = 0.f;

    for (int k0 = k0s; k0 < k0e; k0 += BK) {
        float4 av = make_float4(0.f, 0.f, 0.f, 0.f);
        float4 wv = make_float4(0.f, 0.f, 0.f, 0.f);
        const int ar = row0 + lr;
        if (ar < M) av = *(const float4*)(A + (size_t)ar * lda + k0 + lk);
        const int wr = col0 + lr;
        if (wr < N) wv = *(const float4*)(W + (size_t)wr * ldw + k0 + lk);

        As[lk + 0][lr] = av.x; As[lk + 1][lr] = av.y;
        As[lk + 2][lr] = av.z; As[lk + 3][lr] = av.w;
        Ws[lk + 0][lr] = wv.x; Ws[lk + 1][lr] = wv.y;
        Ws[lk + 2][lr] = wv.z; Ws[lk + 3][lr] = wv.w;
        __syncthreads();

#pragma unroll
        for (int kk = 0; kk < BK; ++kk) {
            float4 a = *(const float4*)&As[kk][ty * 4];
            float4 w = *(const float4*)&Ws[kk][tx * 4];
            float ai[4] = {a.x, a.y, a.z, a.w};
            float wj[4] = {w.x, w.y, w.z, w.w};
#pragma unroll
            for (int i = 0; i < 4; ++i)
#pragma unroll
                for (int j = 0; j < 4; ++j)
                    acc[i][j] = fmaf(ai[i], wj[j], acc[i][j]);
        }
        __syncthreads();
    }

    float* C = P + (size_t)z * M * N;
#pragma unroll
    for (int i = 0; i < 4; ++i) {
        const int r = row0 + ty * 4 + i;
        if (r >= M) continue;
#pragma unroll
        for (int j = 0; j < 4; ++j) {
            const int c = col0 + tx * 4 + j;
            if (c >= N) continue;
            C[(size_t)r * N + c] = acc[i][j];
        }
    }
}

__global__ __launch_bounds__(256)
void reduce_splitk(const float* __restrict__ P, float* __restrict__ out,
                   int total, int nsplit)
{
    const int i = blockIdx.x * 256 + threadIdx.x;
    if (i >= total) return;
    float s = 0.f;
    for (int z = 0; z < nsplit; ++z) s += P[i + (size_t)z * total];
    out[i] = s;
}

// ---------------------------------------------------------------------------
// Chunked parallel scan (unchanged).
// ---------------------------------------------------------------------------
#define NC 32
#define CL 32
#define DI 2048
#define NST 16

__global__ __launch_bounds__(256)
void scan_chunk_local(const float* __restrict__ proj,
                      const float* __restrict__ ssm,
                      const float* __restrict__ dtb,
                      const float* __restrict__ A_log,
                      float* __restrict__ Pf, float* __restrict__ He,
                      float* __restrict__ Pb, float* __restrict__ Gs,
                      float* __restrict__ dtbound)
{
    const int g = blockIdx.x * 256 + threadIdx.x;
    const int d = g & (DI - 1);
    const int r = g >> 11;
    const int c = r & (NC - 1);
    const int b = r >> 5;
    const int t0 = c * CL;
    const size_t rowbase = (size_t)b * 1024;

    float Av[NST];
#pragma unroll
    for (int n = 0; n < NST; ++n) Av[n] = -__expf(A_log[d * NST + n]);

    float h[NST], pf[NST];
#pragma unroll
    for (int n = 0; n < NST; ++n) { h[n] = 0.f; pf[n] = 1.f; }
    for (int t = t0; t < t0 + CL; ++t) {
        const size_t row = rowbase + t;
        const float dtv = dtb[row * DI + d];
        const float hv  = proj[row * 4096 + d];
        const float dh  = dtv * hv;
#pragma unroll
        for (int n = 0; n < NST; ++n) {
            const float Bv = ssm[row * 96 + 64 + n];
            const float dA = __expf(Av[n] * dtv);
            h[n] = fmaf(dA, h[n], dh * Bv);
            pf[n] *= dA;
        }
    }
    const size_t ibase = ((size_t)((b * NC + c) * NST) << 11) + d;
#pragma unroll
    for (int n = 0; n < NST; ++n) {
        Pf[ibase + ((size_t)n << 11)] = pf[n];
        He[ibase + ((size_t)n << 11)] = h[n];
    }

    float dtn = INFINITY;
    const int t1 = t0 + CL;
    if (t1 < 1024) dtn = dtb[(rowbase + t1) * DI + d];
    dtbound[(size_t)(b * NC + c) * DI + d] = dtn;

    float gq[NST], pb[NST], dan[NST];
#pragma unroll
    for (int n = 0; n < NST; ++n) {
        gq[n] = 0.f; pb[n] = 1.f;
        dan[n] = __expf(Av[n] * dtn);
    }
    for (int t = t0 + CL - 1; t >= t0; --t) {
        const size_t row = rowbase + t;
        const float dtv = dtb[row * DI + d];
        const float hv  = proj[row * 4096 + d];
        const float dh  = dtv * hv;
#pragma unroll
        for (int n = 0; n < NST; ++n) {
            const float Bv = ssm[row * 96 + 64 + n];
            gq[n] = fmaf(dan[n], gq[n], dh * Bv);
            pb[n] *= dan[n];
            dan[n] = __expf(Av[n] * dtv);
        }
    }
#pragma unroll
    for (int n = 0; n < NST; ++n) {
        Pb[ibase + ((size_t)n << 11)] = pb[n];
        Gs[ibase + ((size_t)n << 11)] = gq[n];
    }
}

__global__ __launch_bounds__(256)
void scan_combine(const float* __restrict__ Pf, float* __restrict__ He,
                  const float* __restrict__ Pb, float* __restrict__ Gs)
{
    const int g = blockIdx.x * 256 + threadIdx.x;
    const int d = g & (DI - 1);
    const int r = g >> 11;
    const int n = r & (NST - 1);
    const int b = r >> 4;
    const size_t base = ((size_t)(b * NC * NST + n) << 11) + d;
    const size_t cstride = (size_t)NST << 11;

    float H = 0.f;
    for (int c = 0; c < NC; ++c) {
        const size_t i = base + (size_t)c * cstride;
        const float p = Pf[i], e = He[i];
        He[i] = H;
        H = fmaf(p, H, e);
    }
    float G = 0.f;
    for (int c = NC - 1; c >= 0; --c) {
        const size_t i = base + (size_t)c * cstride;
        const float p = Pb[i], s = Gs[i];
        Gs[i] = G;
        G = fmaf(p, G, s);
    }
}

__global__ __launch_bounds__(256)
void scan_apply(const float* __restrict__ proj,
                const float* __restrict__ ssm,
                const float* __restrict__ dtb,
                const float* __restrict__ A_log,
                const float* __restrict__ Dvec,
                const float* __restrict__ He,
                const float* __restrict__ Gs,
                const float* __restrict__ dtbound,
                ushort* __restrict__ sob)
{
    __shared__ float ybuf[256][CL + 1];
    const int tid = threadIdx.x;
    const int g = blockIdx.x * 256 + tid;
    const int d = g & (DI - 1);
    const int r = g >> 11;
    const int c = r & (NC - 1);
    const int b = r >> 5;
    const int t0 = c * CL;
    const size_t rowbase = (size_t)b * 1024;

    float Av[NST];
#pragma unroll
    for (int n = 0; n < NST; ++n) Av[n] = -__expf(A_log[d * NST + n]);
    const size_t ibase = ((size_t)((b * NC + c) * NST) << 11) + d;

    float h[NST];
#pragma unroll
    for (int n = 0; n < NST; ++n) h[n] = He[ibase + ((size_t)n << 11)];
    for (int t = t0; t < t0 + CL; ++t) {
        const size_t row = rowbase + t;
        const float dtv = dtb[row * DI + d];
        const float hv  = proj[row * 4096 + d];
        const float dh  = dtv * hv;
        float y = 0.f;
#pragma unroll
        for (int n = 0; n < NST; ++n) {
            const float Bv = ssm[row * 96 + 64 + n];
            const float Cv = ssm[row * 96 + 80 + n];
            const float dA = __expf(Av[n] * dtv);
            h[n] = fmaf(dA, h[n], dh * Bv);
            y = fmaf(h[n], Cv, y);
        }
        ybuf[tid][t - t0] = y;
    }

    float gq[NST], dan[NST];
#pragma unroll
    for (int n = 0; n < NST; ++n) gq[n] = Gs[ibase + ((size_t)n << 11)];
    {
        const float dtn = dtbound[(size_t)(b * NC + c) * DI + d];
#pragma unroll
        for (int n = 0; n < NST; ++n) dan[n] = __expf(Av[n] * dtn);
    }
    const float Dd = Dvec[d];
    for (int t = t0 + CL - 1; t >= t0; --t) {
        const size_t row = rowbase + t;
        const float dtv = dtb[row * DI + d];
        const float hv  = proj[row * 4096 + d];
        const float dh  = dtv * hv;
        float acc = 0.f;
#pragma unroll
        for (int n = 0; n < NST; ++n) {
            const float Bv = ssm[row * 96 + 64 + n];
            const float Cv = ssm[row * 96 + 80 + n];
            const float u  = dh * Bv;
            gq[n] = fmaf(dan[n], gq[n], u);
            dan[n] = __expf(Av[n] * dtv);
            acc = fmaf(gq[n] - u, Cv, acc);
        }
        const float y   = (ybuf[tid][t - t0] + acc) * 1.3f;
        const float gv  = proj[row * 4096 + DI + d];
        const float sil = gv / (1.f + __expf(-gv));
        const float val = (y + hv * Dd) * sil;
        bf16 hb = __float2bfloat16(val);
        sob[row * DI + d] = *(ushort*)&hb;
    }
}

// ---------------------------------------------------------------------------
extern "C" void kernel_launch(void* const* d_in, const int* in_sizes, int n_in,
                              void* d_out, int out_size, void* d_ws, size_t ws_size,
                              hipStream_t stream)
{
    const float* x     = (const float*)d_in[0];
    const float* Win   = (const float*)d_in[1];
    const float* Wx    = (const float*)d_in[2];
    const float* Wdt   = (const float*)d_in[3];
    const float* bdt   = (const float*)d_in[4];
    const float* A_log = (const float*)d_in[5];
    const float* Dv    = (const float*)d_in[6];
    const float* Wout  = (const float*)d_in[7];
    float* out = (float*)d_out;

    const int B = 2, L = 1024, DM = 1024;
    const int M = B * L;                          // 2048

    // ws layout (float units)
    float* proj = (float*)d_ws;                       // M x 4096
    float* ssm  = proj + (size_t)M * 2 * DI;          // M x 96
    float* dtb  = ssm  + (size_t)M * 96;              // M x 2048
    float* Pf   = dtb  + (size_t)M * DI;
    float* He   = Pf   + (size_t)B * NC * NST * DI;
    float* Pb   = He   + (size_t)B * NC * NST * DI;
    float* Gs   = Pb   + (size_t)B * NC * NST * DI;
    float* dtbd = Gs   + (size_t)B * NC * NST * DI;   // B*NC*2048
    ushort* xb    = (ushort*)(dtbd + (size_t)B * NC * DI);  // M x 1024 bf16
    ushort* Winb  = xb    + (size_t)M * DM;           // 4096 x 1024 bf16
    ushort* Woutb = Winb  + (size_t)(2 * DI) * DM;    // 1024 x 2048 bf16
    ushort* sob   = Woutb + (size_t)DM * DI;          // M x 2048 bf16
    // split-K partials overlay the Pf..Gs region (16 x 2048 x 96 f32 =
    // 12.6 MB < 16.8 MB; GEMM2+reduce finish before scan writes Pf)
    float* part = Pf;

    dim3 blk(256);

    // casts
    cast_bf16<<<dim3((M * DM / 4) / 256), blk, 0, stream>>>(x, xb, M * DM / 4);
    cast_bf16<<<dim3((2 * DI * DM / 4) / 256), blk, 0, stream>>>(Win, Winb, 2 * DI * DM / 4);
    cast_bf16<<<dim3((DM * DI / 4) / 256), blk, 0, stream>>>(Wout, Woutb, DM * DI / 4);

    // 1) proj = x @ Win^T   (MFMA bf16, 2048x4096, K=1024)
    gemm_bf16_mfma<<<dim3((2 * DI) / 128, M / 128), blk, 0, stream>>>(
        (const bf16*)xb, DM, (const bf16*)Winb, DM, proj, 2 * DI, DM);

    // 2) ssm = hidden @ Wx^T  (f32 split-K: 16 splits of K=128)
    gemm_nt_splitk<<<dim3(2, M / BM, 16), blk, 0, stream>>>(
        proj, 2 * DI, Wx, DI, part, M, 96, DI, DI / 16);
    reduce_splitk<<<dim3((M * 96 + 255) / 256), blk, 0, stream>>>(
        part, ssm, M * 96, 16);

    // 3) dtb = softplus(ssm[:, :64] @ Wdt^T + bdt)  (f32, 2048x2048, K=64)
    gemm_nt<<<dim3(DI / BN, M / BM), blk, 0, stream>>>(
        ssm, 96, Wdt, 64, dtb, DI, M, DI, 64, bdt, 1);

    // 4) scan
    scan_chunk_local<<<dim3((B * DI * NC) / 256), blk, 0, stream>>>(
        proj, ssm, dtb, A_log, Pf, He, Pb, Gs, dtbd);
    scan_combine<<<dim3((B * DI * NST) / 256), blk, 0, stream>>>(Pf, He, Pb, Gs);
    scan_apply<<<dim3((B * DI * NC) / 256), blk, 0, stream>>>(
        proj, ssm, dtb, A_log, Dv, He, Gs, dtbd, sob);

    // 5) out = scan_out @ Wout^T  (MFMA bf16, 2048x1024, K=2048)
    gemm_bf16_mfma<<<dim3(DM / 128, M / 128), blk, 0, stream>>>(
        (const bf16*)sob, DI, (const bf16*)Woutb, DI, out, DM, DI);
}

// Round 7
// 308.909 us; speedup vs baseline: 5.7215x; 1.0198x over previous
//
#include <hip/hip_runtime.h>
#include <hip/hip_bf16.h>
#include <cstdint>
#include <cstddef>

typedef __hip_bfloat16 bf16;
typedef __attribute__((ext_vector_type(8))) short short8v;
typedef __attribute__((ext_vector_type(4))) float f32x4;

// ---------------------------------------------------------------------------
// f32 -> bf16 cast, float4 in / ushort4 out
// ---------------------------------------------------------------------------
__global__ __launch_bounds__(256)
void cast_bf16(const float* __restrict__ in, ushort* __restrict__ out, int n4)
{
    const int i = blockIdx.x * 256 + threadIdx.x;
    if (i >= n4) return;
    const float4 v = ((const float4*)in)[i];
    ushort4 o;
    bf16 h;
    h = __float2bfloat16(v.x); o.x = *(ushort*)&h;
    h = __float2bfloat16(v.y); o.y = *(ushort*)&h;
    h = __float2bfloat16(v.z); o.z = *(ushort*)&h;
    h = __float2bfloat16(v.w); o.w = *(ushort*)&h;
    ((ushort4*)out)[i] = o;
}

// ---------------------------------------------------------------------------
// bf16 MFMA NT GEMM: C[M,N](f32) = A[M,K] @ W[N,K]^T, both bf16 row-major.
// 128x128 tile, BK=32, 256 thr = 4 waves (2x2), 4x4 16x16x32 frags per wave.
// ---------------------------------------------------------------------------
__global__ __launch_bounds__(256)
void gemm_bf16_mfma(const bf16* __restrict__ A, int lda,
                    const bf16* __restrict__ W, int ldw,
                    float* __restrict__ C, int ldc, int K)
{
    __shared__ short Asl[128 * 32];
    __shared__ short Wsl[128 * 32];
    const int tid = threadIdx.x;
    const int lane = tid & 63, wave = tid >> 6;
    const int row0 = blockIdx.y * 128, col0 = blockIdx.x * 128;
    const int wr = wave >> 1, wc = wave & 1;
    const int lr = lane & 15, lq = lane >> 4;

    f32x4 acc[4][4] = {};

    for (int k0 = 0; k0 < K; k0 += 32) {
#pragma unroll
        for (int i = 0; i < 2; ++i) {
            const int o = ((i * 4 + wave) << 9) + lane * 8;
            const int r = o >> 5, kk = o & 31;
            __builtin_amdgcn_global_load_lds(
                (const __attribute__((address_space(1))) void*)(A + (size_t)(row0 + r) * lda + k0 + kk),
                (__attribute__((address_space(3))) void*)(Asl + (((i * 4 + wave) << 9))),
                16, 0, 0);
            __builtin_amdgcn_global_load_lds(
                (const __attribute__((address_space(1))) void*)(W + (size_t)(col0 + r) * ldw + k0 + kk),
                (__attribute__((address_space(3))) void*)(Wsl + (((i * 4 + wave) << 9))),
                16, 0, 0);
        }
        __syncthreads();

        short8v af[4], wf[4];
#pragma unroll
        for (int m = 0; m < 4; ++m)
            af[m] = *(const short8v*)&Asl[(wr * 64 + m * 16 + lr) * 32 + lq * 8];
#pragma unroll
        for (int n = 0; n < 4; ++n)
            wf[n] = *(const short8v*)&Wsl[(wc * 64 + n * 16 + lr) * 32 + lq * 8];
#pragma unroll
        for (int m = 0; m < 4; ++m)
#pragma unroll
            for (int n = 0; n < 4; ++n)
                acc[m][n] = __builtin_amdgcn_mfma_f32_16x16x32_bf16(af[m], wf[n], acc[m][n], 0, 0, 0);
        __syncthreads();
    }

#pragma unroll
    for (int m = 0; m < 4; ++m) {
        const int r = row0 + wr * 64 + m * 16 + lq * 4;
#pragma unroll
        for (int n = 0; n < 4; ++n) {
            const int c = col0 + wc * 64 + n * 16 + lr;
#pragma unroll
            for (int j = 0; j < 4; ++j)
                C[(size_t)(r + j) * ldc + c] = acc[m][n][j];
        }
    }
}

// ---------------------------------------------------------------------------
// f32 NT GEMM: C = A @ W^T.  mode 1: softplus(acc+bias)
// ---------------------------------------------------------------------------
#define BM 64
#define BN 64
#define BK 16
#define BMP 68
#define BNP 68

__global__ __launch_bounds__(256)
void gemm_nt(const float* __restrict__ A, int lda,
             const float* __restrict__ W, int ldw,
             float* __restrict__ C, int ldc,
             int M, int N, int K,
             const float* __restrict__ bias, int mode)
{
    __shared__ float As[BK][BMP];
    __shared__ float Ws[BK][BNP];

    const int tid  = threadIdx.x;
    const int row0 = blockIdx.y * BM;
    const int col0 = blockIdx.x * BN;
    const int lr = tid >> 2;
    const int lk = (tid & 3) << 2;
    const int tx = tid & 15;
    const int ty = tid >> 4;

    float acc[4][4];
#pragma unroll
    for (int i = 0; i < 4; ++i)
#pragma unroll
        for (int j = 0; j < 4; ++j) acc[i][j] = 0.f;

    for (int k0 = 0; k0 < K; k0 += BK) {
        float4 av = make_float4(0.f, 0.f, 0.f, 0.f);
        float4 wv = make_float4(0.f, 0.f, 0.f, 0.f);
        const int ar = row0 + lr;
        if (ar < M) av = *(const float4*)(A + (size_t)ar * lda + k0 + lk);
        const int wr = col0 + lr;
        if (wr < N) wv = *(const float4*)(W + (size_t)wr * ldw + k0 + lk);

        As[lk + 0][lr] = av.x; As[lk + 1][lr] = av.y;
        As[lk + 2][lr] = av.z; As[lk + 3][lr] = av.w;
        Ws[lk + 0][lr] = wv.x; Ws[lk + 1][lr] = wv.y;
        Ws[lk + 2][lr] = wv.z; Ws[lk + 3][lr] = wv.w;
        __syncthreads();

#pragma unroll
        for (int kk = 0; kk < BK; ++kk) {
            float4 a = *(const float4*)&As[kk][ty * 4];
            float4 w = *(const float4*)&Ws[kk][tx * 4];
            float ai[4] = {a.x, a.y, a.z, a.w};
            float wj[4] = {w.x, w.y, w.z, w.w};
#pragma unroll
            for (int i = 0; i < 4; ++i)
#pragma unroll
                for (int j = 0; j < 4; ++j)
                    acc[i][j] = fmaf(ai[i], wj[j], acc[i][j]);
        }
        __syncthreads();
    }

#pragma unroll
    for (int i = 0; i < 4; ++i) {
        const int r = row0 + ty * 4 + i;
        if (r >= M) continue;
#pragma unroll
        for (int j = 0; j < 4; ++j) {
            const int c = col0 + tx * 4 + j;
            if (c >= N) continue;
            float v = acc[i][j];
            if (mode == 1) {
                v += bias[c];
                v = (v > 20.f) ? v : log1pf(__expf(v));
            }
            C[(size_t)r * ldc + c] = v;
        }
    }
}

// ---------------------------------------------------------------------------
// Split-K f32 NT GEMM (GEMM2: 2048x96, K=2048).
// ---------------------------------------------------------------------------
__global__ __launch_bounds__(256)
void gemm_nt_splitk(const float* __restrict__ A, int lda,
                    const float* __restrict__ W, int ldw,
                    float* __restrict__ P,
                    int M, int N, int K, int ksplit)
{
    __shared__ float As[BK][BMP];
    __shared__ float Ws[BK][BNP];

    const int tid  = threadIdx.x;
    const int row0 = blockIdx.y * BM;
    const int col0 = blockIdx.x * BN;
    const int z    = blockIdx.z;
    const int k0s = z * ksplit, k0e = k0s + ksplit;
    const int lr = tid >> 2;
    const int lk = (tid & 3) << 2;
    const int tx = tid & 15;
    const int ty = tid >> 4;

    float acc[4][4];
#pragma unroll
    for (int i = 0; i < 4; ++i)
#pragma unroll
        for (int j = 0; j < 4; ++j) acc[i][j] = 0.f;

    for (int k0 = k0s; k0 < k0e; k0 += BK) {
        float4 av = make_float4(0.f, 0.f, 0.f, 0.f);
        float4 wv = make_float4(0.f, 0.f, 0.f, 0.f);
        const int ar = row0 + lr;
        if (ar < M) av = *(const float4*)(A + (size_t)ar * lda + k0 + lk);
        const int wr = col0 + lr;
        if (wr < N) wv = *(const float4*)(W + (size_t)wr * ldw + k0 + lk);

        As[lk + 0][lr] = av.x; As[lk + 1][lr] = av.y;
        As[lk + 2][lr] = av.z; As[lk + 3][lr] = av.w;
        Ws[lk + 0][lr] = wv.x; Ws[lk + 1][lr] = wv.y;
        Ws[lk + 2][lr] = wv.z; Ws[lk + 3][lr] = wv.w;
        __syncthreads();

#pragma unroll
        for (int kk = 0; kk < BK; ++kk) {
            float4 a = *(const float4*)&As[kk][ty * 4];
            float4 w = *(const float4*)&Ws[kk][tx * 4];
            float ai[4] = {a.x, a.y, a.z, a.w};
            float wj[4] = {w.x, w.y, w.z, w.w};
#pragma unroll
            for (int i = 0; i < 4; ++i)
#pragma unroll
                for (int j = 0; j < 4; ++j)
                    acc[i][j] = fmaf(ai[i], wj[j], acc[i][j]);
        }
        __syncthreads();
    }

    float* C = P + (size_t)z * M * N;
#pragma unroll
    for (int i = 0; i < 4; ++i) {
        const int r = row0 + ty * 4 + i;
        if (r >= M) continue;
#pragma unroll
        for (int j = 0; j < 4; ++j) {
            const int c = col0 + tx * 4 + j;
            if (c >= N) continue;
            C[(size_t)r * N + c] = acc[i][j];
        }
    }
}

__global__ __launch_bounds__(256)
void reduce_splitk(const float* __restrict__ P, float* __restrict__ out,
                   int total, int nsplit)
{
    const int i = blockIdx.x * 256 + threadIdx.x;
    if (i >= total) return;
    float s = 0.f;
    for (int z = 0; z < nsplit; ++z) s += P[i + (size_t)z * total];
    out[i] = s;
}

// ---------------------------------------------------------------------------
// Chunked parallel scan, half-state split: thread = (b, c, d, half);
// half owns states n0..n0+7, lane pair (lane^1) owns the other 8.
// S1 is SINGLE-PASS: backward chunk-locals are forward-computable:
//   Gs = sum_s (prod_{j=t0+1..s} dA_j) u_s   (running product pq)
//   Pb = pq_end * dA_boundary
// ---------------------------------------------------------------------------
#define NC 32
#define CL 32
#define DI 2048
#define NST 16

__global__ __launch_bounds__(256)
void scan_chunk_local(const float* __restrict__ proj,
                      const float* __restrict__ ssm,
                      const float* __restrict__ dtb,
                      const float* __restrict__ A_log,
                      float* __restrict__ Pf, float* __restrict__ He,
                      float* __restrict__ Pb, float* __restrict__ Gs,
                      float* __restrict__ dtbound)
{
    const int g = blockIdx.x * 256 + threadIdx.x;   // B*DI*NC*2 threads
    const int half = g & 1;
    const int d = (g >> 1) & (DI - 1);
    const int r = g >> 12;
    const int c = r & (NC - 1);
    const int b = r >> 5;
    const int t0 = c * CL;
    const int n0 = half * 8;
    const size_t rowbase = (size_t)b * 1024;

    float Av[8];
#pragma unroll
    for (int n = 0; n < 8; ++n) Av[n] = -__expf(A_log[d * NST + n0 + n]);

    float h[8], pf[8], gs[8], pq[8];
    {   // t = t0 (peeled: pq=1, gs=u, pf=dA, h=u)
        const size_t row = rowbase + t0;
        const float dtv = dtb[row * DI + d];
        const float hv  = proj[row * 4096 + d];
        const float dh  = dtv * hv;
#pragma unroll
        for (int n = 0; n < 8; ++n) {
            const float Bv = ssm[row * 96 + 64 + n0 + n];
            const float u  = dh * Bv;
            pf[n] = __expf(Av[n] * dtv);
            h[n] = u; gs[n] = u; pq[n] = 1.f;
        }
    }
    for (int t = t0 + 1; t < t0 + CL; ++t) {
        const size_t row = rowbase + t;
        const float dtv = dtb[row * DI + d];
        const float hv  = proj[row * 4096 + d];
        const float dh  = dtv * hv;
#pragma unroll
        for (int n = 0; n < 8; ++n) {
            const float Bv = ssm[row * 96 + 64 + n0 + n];
            const float dA = __expf(Av[n] * dtv);
            const float u  = dh * Bv;
            h[n]  = fmaf(dA, h[n], u);
            pf[n] *= dA;
            pq[n] *= dA;
            gs[n] = fmaf(pq[n], u, gs[n]);
        }
    }

    float dtn = INFINITY;                 // exp(Av*inf)=0 kills the seq tail
    const int t1 = t0 + CL;
    if (t1 < 1024) dtn = dtb[(rowbase + t1) * DI + d];
    if (half == 0) dtbound[(size_t)(b * NC + c) * DI + d] = dtn;

    const size_t ibase = ((size_t)((b * NC + c) * NST) << 11) + d;
#pragma unroll
    for (int n = 0; n < 8; ++n) {
        const float dAb = __expf(Av[n] * dtn);
        const size_t o = ibase + ((size_t)(n0 + n) << 11);
        Pf[o] = pf[n];
        He[o] = h[n];
        Pb[o] = pq[n] * dAb;
        Gs[o] = gs[n];
    }
}

__global__ __launch_bounds__(256)
void scan_combine(const float* __restrict__ Pf, float* __restrict__ He,
                  const float* __restrict__ Pb, float* __restrict__ Gs)
{
    const int g = blockIdx.x * 256 + threadIdx.x;
    const int d = g & (DI - 1);
    const int r = g >> 11;
    const int n = r & (NST - 1);
    const int b = r >> 4;
    const size_t base = ((size_t)(b * NC * NST + n) << 11) + d;
    const size_t cstride = (size_t)NST << 11;

    float H = 0.f;
    for (int c = 0; c < NC; ++c) {
        const size_t i = base + (size_t)c * cstride;
        const float p = Pf[i], e = He[i];
        He[i] = H;
        H = fmaf(p, H, e);
    }
    float G = 0.f;
    for (int c = NC - 1; c >= 0; --c) {
        const size_t i = base + (size_t)c * cstride;
        const float p = Pb[i], s = Gs[i];
        Gs[i] = G;
        G = fmaf(p, G, s);
    }
}

__global__ __launch_bounds__(256)
void scan_apply(const float* __restrict__ proj,
                const float* __restrict__ ssm,
                const float* __restrict__ dtb,
                const float* __restrict__ A_log,
                const float* __restrict__ Dvec,
                const float* __restrict__ He,
                const float* __restrict__ Gs,
                const float* __restrict__ dtbound,
                ushort* __restrict__ sob)
{
    __shared__ float ybuf[256][CL + 1];
    const int tid = threadIdx.x;
    const int g = blockIdx.x * 256 + tid;
    const int half = g & 1;
    const int d = (g >> 1) & (DI - 1);
    const int r = g >> 12;
    const int c = r & (NC - 1);
    const int b = r >> 5;
    const int t0 = c * CL;
    const int n0 = half * 8;
    const size_t rowbase = (size_t)b * 1024;

    float Av[8];
#pragma unroll
    for (int n = 0; n < 8; ++n) Av[n] = -__expf(A_log[d * NST + n0 + n]);
    const size_t ibase = ((size_t)((b * NC + c) * NST) << 11) + d;

    // ---- forward apply: y per t (combined across the lane pair) ----
    float h[8];
#pragma unroll
    for (int n = 0; n < 8; ++n) h[n] = He[ibase + ((size_t)(n0 + n) << 11)];
    for (int i = 0; i < CL; ++i) {
        const size_t row = rowbase + t0 + i;
        const float dtv = dtb[row * DI + d];
        const float hv  = proj[row * 4096 + d];
        const float dh  = dtv * hv;
        float y = 0.f;
#pragma unroll
        for (int n = 0; n < 8; ++n) {
            const float Bv = ssm[row * 96 + 64 + n0 + n];
            const float Cv = ssm[row * 96 + 80 + n0 + n];
            const float dA = __expf(Av[n] * dtv);
            h[n] = fmaf(dA, h[n], dh * Bv);
            y = fmaf(h[n], Cv, y);
        }
        ybuf[tid][i] = y + __shfl_xor(y, 1);
    }

    // ---- backward apply + finalize ----
    float gq[8], dan[8];
#pragma unroll
    for (int n = 0; n < 8; ++n) gq[n] = Gs[ibase + ((size_t)(n0 + n) << 11)];
    {
        const float dtn = dtbound[(size_t)(b * NC + c) * DI + d];
#pragma unroll
        for (int n = 0; n < 8; ++n) dan[n] = __expf(Av[n] * dtn);
    }
    const float Dd = Dvec[d];
    for (int i = CL - 1; i >= 0; --i) {
        const size_t row = rowbase + t0 + i;
        const float dtv = dtb[row * DI + d];
        const float hv  = proj[row * 4096 + d];
        const float dh  = dtv * hv;
        float acc = 0.f;
#pragma unroll
        for (int n = 0; n < 8; ++n) {
            const float Bv = ssm[row * 96 + 64 + n0 + n];
            const float Cv = ssm[row * 96 + 80 + n0 + n];
            const float u  = dh * Bv;
            gq[n] = fmaf(dan[n], gq[n], u);
            dan[n] = __expf(Av[n] * dtv);
            acc = fmaf(gq[n] - u, Cv, acc);
        }
        acc += __shfl_xor(acc, 1);
        if (half == 0) {
            const float y   = (ybuf[tid][i] + acc) * 1.3f;
            const float gv  = proj[row * 4096 + DI + d];
            const float sil = gv / (1.f + __expf(-gv));
            const float val = (y + hv * Dd) * sil;
            bf16 hb = __float2bfloat16(val);
            sob[row * DI + d] = *(ushort*)&hb;
        }
    }
}

// ---------------------------------------------------------------------------
extern "C" void kernel_launch(void* const* d_in, const int* in_sizes, int n_in,
                              void* d_out, int out_size, void* d_ws, size_t ws_size,
                              hipStream_t stream)
{
    const float* x     = (const float*)d_in[0];
    const float* Win   = (const float*)d_in[1];
    const float* Wx    = (const float*)d_in[2];
    const float* Wdt   = (const float*)d_in[3];
    const float* bdt   = (const float*)d_in[4];
    const float* A_log = (const float*)d_in[5];
    const float* Dv    = (const float*)d_in[6];
    const float* Wout  = (const float*)d_in[7];
    float* out = (float*)d_out;

    const int B = 2, L = 1024, DM = 1024;
    const int M = B * L;                          // 2048

    // ws layout (float units)
    float* proj = (float*)d_ws;                       // M x 4096
    float* ssm  = proj + (size_t)M * 2 * DI;          // M x 96
    float* dtb  = ssm  + (size_t)M * 96;              // M x 2048
    float* Pf   = dtb  + (size_t)M * DI;
    float* He   = Pf   + (size_t)B * NC * NST * DI;
    float* Pb   = He   + (size_t)B * NC * NST * DI;
    float* Gs   = Pb   + (size_t)B * NC * NST * DI;
    float* dtbd = Gs   + (size_t)B * NC * NST * DI;   // B*NC*2048
    ushort* xb    = (ushort*)(dtbd + (size_t)B * NC * DI);  // M x 1024 bf16
    ushort* Winb  = xb    + (size_t)M * DM;           // 4096 x 1024 bf16
    ushort* Woutb = Winb  + (size_t)(2 * DI) * DM;    // 1024 x 2048 bf16
    ushort* sob   = Woutb + (size_t)DM * DI;          // M x 2048 bf16
    // split-K partials overlay the Pf..Gs region (dead until scan S1)
    float* part = Pf;

    dim3 blk(256);

    // casts
    cast_bf16<<<dim3((M * DM / 4) / 256), blk, 0, stream>>>(x, xb, M * DM / 4);
    cast_bf16<<<dim3((2 * DI * DM / 4) / 256), blk, 0, stream>>>(Win, Winb, 2 * DI * DM / 4);
    cast_bf16<<<dim3((DM * DI / 4) / 256), blk, 0, stream>>>(Wout, Woutb, DM * DI / 4);

    // 1) proj = x @ Win^T   (MFMA bf16, 2048x4096, K=1024)
    gemm_bf16_mfma<<<dim3((2 * DI) / 128, M / 128), blk, 0, stream>>>(
        (const bf16*)xb, DM, (const bf16*)Winb, DM, proj, 2 * DI, DM);

    // 2) ssm = hidden @ Wx^T  (f32 split-K: 16 splits of K=128)
    gemm_nt_splitk<<<dim3(2, M / BM, 16), blk, 0, stream>>>(
        proj, 2 * DI, Wx, DI, part, M, 96, DI, DI / 16);
    reduce_splitk<<<dim3((M * 96 + 255) / 256), blk, 0, stream>>>(
        part, ssm, M * 96, 16);

    // 3) dtb = softplus(ssm[:, :64] @ Wdt^T + bdt)  (f32, 2048x2048, K=64)
    gemm_nt<<<dim3(DI / BN, M / BM), blk, 0, stream>>>(
        ssm, 96, Wdt, 64, dtb, DI, M, DI, 64, bdt, 1);

    // 4) scan: single-pass locals -> combine -> apply (half-state split grids)
    scan_chunk_local<<<dim3((B * DI * NC * 2) / 256), blk, 0, stream>>>(
        proj, ssm, dtb, A_log, Pf, He, Pb, Gs, dtbd);
    scan_combine<<<dim3((B * DI * NST) / 256), blk, 0, stream>>>(Pf, He, Pb, Gs);
    scan_apply<<<dim3((B * DI * NC * 2) / 256), blk, 0, stream>>>(
        proj, ssm, dtb, A_log, Dv, He, Gs, dtbd, sob);

    // 5) out = scan_out @ Wout^T  (MFMA bf16, 2048x1024, K=2048)
    gemm_bf16_mfma<<<dim3(DM / 128, M / 128), blk, 0, stream>>>(
        (const bf16*)sob, DI, (const bf16*)Woutb, DI, out, DM, DI);
}